// Round 2
// baseline (446.606 us; speedup 1.0000x reference)
//
#include <hip/hip_runtime.h>
#include <hip/hip_bf16.h>

// Depthwise 3x3 conv, filter indexed by b only:
// out[b,c,h,w] = sum_{kh,kw} x[b,c,h+kh-1,w+kw-1] * kernel[b,kh,kw]
// x: (16,64,256,256) fp32, kernel: (16,3,3) fp32, out: same as x.
//
// R1: 10 VMEM/quad, latency-bound at 2.25 TB/s (36% achievable).
// R2: halo via __shfl (lane==w4 spans full W row), 4x h-blocking:
//     6 dwordx4 loads + 4 dwordx4 stores per 16 outputs. (~94 us conv; the
//     430 us dur_us includes ~336 us of harness poison-fills.)
// R3: 8x h-blocking (32 rows/block) -> inter-block read amplification
//     1.125x -> 1.0625x; all 10 row-loads issued up-front for MLP;
//     nontemporal stores keep L2 for the cross-block halo rows.
// R4: fix compile — nontemporal builtin needs a native ext_vector_type,
//     not HIP_vector_type<float,4>.

#define CC 64
#define HH 256
#define WW 256
#define ROWS 8          // output rows per thread (one wave = 64 lanes = full W row)

typedef float vf4 __attribute__((ext_vector_type(4)));

__global__ __launch_bounds__(256) void ParConv2d_dw3x3(
    const float* __restrict__ x,
    const float* __restrict__ kern,
    float* __restrict__ out)
{
    const int tid  = threadIdx.x;
    const int lane = tid & 63;      // lane == w4; 64 lanes * 4 floats = full W row
    const int wave = tid >> 6;      // 4 waves per block -> 32 rows per block
    const int tile = blockIdx.x & 7;    // 8 h-tiles of 32 rows each
    const int bc   = blockIdx.x >> 3;   // b*C + c
    const int b    = bc >> 6;           // C = 64

    // 9 filter taps: b is block-uniform -> scalar loads
    const float* kb = kern + b * 9;
    const float k00 = kb[0], k01 = kb[1], k02 = kb[2];
    const float k10 = kb[3], k11 = kb[4], k12 = kb[5];
    const float k20 = kb[6], k21 = kb[7], k22 = kb[8];

    const float* xp = x + (size_t)bc * (HH * WW);
    const int h0 = tile * 32 + wave * ROWS;   // first output row of this thread
    const int w0 = lane << 2;

    // Issue all ROWS+2 row-loads first: max memory-level parallelism.
    float4 v[ROWS + 2];
#pragma unroll
    for (int r = 0; r < ROWS + 2; ++r) {
        const int hh = h0 + r - 1;
        v[r] = make_float4(0.f, 0.f, 0.f, 0.f);
        if (hh >= 0 && hh < HH) {              // wave-uniform branch
            v[r] = *(const float4*)(xp + hh * WW + w0);
        }
    }

    // win[r][j] = x[h0+r-1][w0-1+j], r in 0..ROWS+1, j in 0..5, zero-padded.
    float win[ROWS + 2][6];
#pragma unroll
    for (int r = 0; r < ROWS + 2; ++r) {
        const float l  = __shfl_up(v[r].w, 1);     // lane-1's last element
        const float rr = __shfl_down(v[r].x, 1);   // lane+1's first element
        win[r][0] = (lane == 0)  ? 0.f : l;
        win[r][1] = v[r].x; win[r][2] = v[r].y; win[r][3] = v[r].z; win[r][4] = v[r].w;
        win[r][5] = (lane == 63) ? 0.f : rr;
    }

    float* op = out + (size_t)bc * (HH * WW) + (size_t)h0 * WW + w0;
#pragma unroll
    for (int orow = 0; orow < ROWS; ++orow) {
        float res[4];
#pragma unroll
        for (int j = 0; j < 4; ++j) {
            res[j] = k00 * win[orow][j]     + k01 * win[orow][j + 1]     + k02 * win[orow][j + 2]
                   + k10 * win[orow + 1][j] + k11 * win[orow + 1][j + 1] + k12 * win[orow + 1][j + 2]
                   + k20 * win[orow + 2][j] + k21 * win[orow + 2][j + 1] + k22 * win[orow + 2][j + 2];
        }
        // Output is never re-read: bypass caches, keep L2 for halo rows.
        vf4 rv; rv.x = res[0]; rv.y = res[1]; rv.z = res[2]; rv.w = res[3];
        __builtin_nontemporal_store(rv, (vf4*)(op + orow * WW));
    }
}

extern "C" void kernel_launch(void* const* d_in, const int* in_sizes, int n_in,
                              void* d_out, int out_size, void* d_ws, size_t ws_size,
                              hipStream_t stream) {
    const float* x    = (const float*)d_in[0];
    const float* kern = (const float*)d_in[1];
    float* out        = (float*)d_out;

    // grid: (b*C) images x 8 h-tiles (32 rows); block: 4 waves x 64 lanes
    const int blocks = 16 * CC * 8;   // 8192
    ParConv2d_dw3x3<<<blocks, 256, 0, stream>>>(x, kern, out);
}

// Round 3
// 435.817 us; speedup vs baseline: 1.0248x; 1.0248x over previous
//
#include <hip/hip_runtime.h>
#include <hip/hip_bf16.h>

// Depthwise 3x3 conv, filter indexed by b only:
// out[b,c,h,w] = sum_{kh,kw} x[b,c,h+kh-1,w+kw-1] * kernel[b,kh,kw]
// x: (16,64,256,256) fp32, kernel: (16,3,3) fp32, out: same as x.
//
// R1: 10 VMEM/quad, latency-bound at 2.25 TB/s (36% achievable).
// R2: halo via __shfl (lane==w4 spans full W row), 4x h-blocking:
//     6 dwordx4 loads + 4 dwordx4 stores per 16 outputs. 429.8 us total
//     (~94 us conv; ~336 us is harness poison-fills).
// R3/R4: ROWS=8 + NT stores REGRESSED (446.6 us): ~120 VGPR halved
//     occupancy for a ~3 us halo saving. Reverted.
// R5: R2 structure + bijective XCD-chunk swizzle: adjacent h-tiles of the
//     same image land on the SAME XCD's L2 -> the 2 shared halo rows per
//     16-row tile become L2 hits instead of HBM re-fetches (1.125x -> ~1.0x).

#define CC 64
#define HH 256
#define WW 256

__global__ __launch_bounds__(256) void ParConv2d_dw3x3(
    const float* __restrict__ x,
    const float* __restrict__ kern,
    float* __restrict__ out)
{
    // XCD-aware swizzle: hardware round-robins blockIdx across 8 XCDs.
    // lb = (blk%8)*(16384/8) + blk/8 gives each XCD a contiguous 2048-block
    // chunk of (image, tile) space, processed stride-1 in time.
    const int blk = blockIdx.x;
    const int lb  = (blk & 7) * (16384 >> 3) + (blk >> 3);

    const int tid  = threadIdx.x;
    const int lane = tid & 63;      // lane == w4; 64 lanes * 4 floats = full W row
    const int wave = tid >> 6;      // 4 waves per block
    const int tile = lb & 15;       // 16 h-tiles of 16 rows each
    const int bc   = lb >> 4;       // b*C + c
    const int b    = bc >> 6;       // C = 64

    // 9 filter taps: b is block-uniform -> scalar loads
    const float* kb = kern + b * 9;
    const float k00 = kb[0], k01 = kb[1], k02 = kb[2];
    const float k10 = kb[3], k11 = kb[4], k12 = kb[5];
    const float k20 = kb[6], k21 = kb[7], k22 = kb[8];

    const float* xp = x + (size_t)bc * (HH * WW);
    const int h0 = tile * 16 + wave * 4;   // first output row of this thread
    const int w0 = lane << 2;

    // win[r][j] = x[h0+r-1][w0-1+j], r in 0..5, j in 0..5, zero-padded.
    float win[6][6];
#pragma unroll
    for (int r = 0; r < 6; ++r) {
        const int hh = h0 + r - 1;
        float4 v = make_float4(0.f, 0.f, 0.f, 0.f);
        if (hh >= 0 && hh < HH) {          // wave-uniform branch
            v = *(const float4*)(xp + hh * WW + w0);
        }
        const float l = __shfl_up(v.w, 1);     // lane-1's last element
        const float rr = __shfl_down(v.x, 1);  // lane+1's first element
        win[r][0] = (lane == 0)  ? 0.f : l;
        win[r][1] = v.x; win[r][2] = v.y; win[r][3] = v.z; win[r][4] = v.w;
        win[r][5] = (lane == 63) ? 0.f : rr;
    }

    float* op = out + (size_t)bc * (HH * WW) + (size_t)h0 * WW + w0;
#pragma unroll
    for (int orow = 0; orow < 4; ++orow) {
        float res[4];
#pragma unroll
        for (int j = 0; j < 4; ++j) {
            res[j] = k00 * win[orow][j]     + k01 * win[orow][j + 1]     + k02 * win[orow][j + 2]
                   + k10 * win[orow + 1][j] + k11 * win[orow + 1][j + 1] + k12 * win[orow + 1][j + 2]
                   + k20 * win[orow + 2][j] + k21 * win[orow + 2][j + 1] + k22 * win[orow + 2][j + 2];
        }
        *(float4*)(op + orow * WW) = make_float4(res[0], res[1], res[2], res[3]);
    }
}

extern "C" void kernel_launch(void* const* d_in, const int* in_sizes, int n_in,
                              void* d_out, int out_size, void* d_ws, size_t ws_size,
                              hipStream_t stream) {
    const float* x    = (const float*)d_in[0];
    const float* kern = (const float*)d_in[1];
    float* out        = (float*)d_out;

    // grid: (b*C) images x 16 h-tiles; block: 4 waves x 64 lanes
    const int blocks = 16 * CC * 16;   // 16384
    ParConv2d_dw3x3<<<blocks, 256, 0, stream>>>(x, kern, out);
}